// Round 7
// baseline (138.800 us; speedup 1.0000x reference)
//
#include <hip/hip_runtime.h>
#include <hip/hip_fp16.h>
#include <math.h>

#define TB 2048
#define TK 128
#define TD 512
#define DSPLIT 32
#define DLEN 16            // TD / DSPLIT
#define BROWS 64
#define NRB (TB / BROWS)   // 32

// ws layout: [0, 16MB) part[ds][b][k] as __half ; [16MB, +16KB) logdet_part[ds][k] f32

// ---------------------------------------------------------------------------
// dist kernel: block = 64 rows x 128 k x 16 d slice; 256 threads (4 waves).
// grid = 32 x 32 = 1024 blocks = 4 blocks/CU = 16 waves/CU (4/SIMD).
// Thread tile = 4 rows x 8 k. One-shot LDS staging, one barrier, pure FMA.
// Partials written as f16 (half the finish-kernel traffic).
// ---------------------------------------------------------------------------
__global__ __launch_bounds__(256, 4) void dist_kernel(
        const float* __restrict__ x, const float* __restrict__ C,
        const float* __restrict__ Dm, __half* __restrict__ part,
        float* __restrict__ logdet_part) {
    __shared__ float sa[DLEN][TK];    // 8 KB : u = rsqrt(|D|+eps), [d][k]
    __shared__ float sb[DLEN][TK];    // 8 KB : c*u, [d][k]
    __shared__ float xs[DLEN][BROWS]; // 4 KB : x tile transposed, [d][row]

    const int tid = threadIdx.x;
    const int rb = blockIdx.x / DSPLIT;
    const int ds = blockIdx.x % DSPLIT;
    const int b0 = rb * BROWS;
    const int d0 = ds * DLEN;

    // ---- stage x tile transposed: 64 rows x 16 d = 256 float4, 1/thread ----
    {
        int row = tid >> 2;            // 0..63
        int dq = (tid & 3) * 4;        // 0,4,8,12
        float4 v = *reinterpret_cast<const float4*>(
            &x[(size_t)(b0 + row) * TD + d0 + dq]);
        xs[dq + 0][row] = v.x;
        xs[dq + 1][row] = v.y;
        xs[dq + 2][row] = v.z;
        xs[dq + 3][row] = v.w;
    }

    // ---- stage params: 128 k x 4 f4 = 512 f4, 2 per thread (coalesced) ----
    #pragma unroll
    for (int i = 0; i < 2; ++i) {
        int f = i * 256 + tid;        // 0..511
        int k = f >> 2;               // 0..127
        int j = f & 3;                // f4 index within k's 16-d slice
        float4 dv = *reinterpret_cast<const float4*>(&Dm[(size_t)k * TD + d0 + j * 4]);
        float4 cv = *reinterpret_cast<const float4*>(&C[(size_t)k * TD + d0 + j * 4]);
        float da0 = fabsf(dv.x) + 1e-8f, u0 = rsqrtf(da0);
        float da1 = fabsf(dv.y) + 1e-8f, u1 = rsqrtf(da1);
        float da2 = fabsf(dv.z) + 1e-8f, u2 = rsqrtf(da2);
        float da3 = fabsf(dv.w) + 1e-8f, u3 = rsqrtf(da3);
        int db = j * 4;
        sa[db + 0][k] = u0; sb[db + 0][k] = cv.x * u0;
        sa[db + 1][k] = u1; sb[db + 1][k] = cv.y * u1;
        sa[db + 2][k] = u2; sb[db + 2][k] = cv.z * u2;
        sa[db + 3][k] = u3; sb[db + 3][k] = cv.w * u3;
        if (rb == 0) {
            // 4 consecutive lanes (j=0..3) share k: reduce, lane j==0 writes.
            float ls = logf(da0) + logf(da1) + logf(da2) + logf(da3);
            ls += __shfl_xor(ls, 1, 64);
            ls += __shfl_xor(ls, 2, 64);
            if ((tid & 3) == 0) logdet_part[ds * TK + k] = -0.5f * ls;
        }
    }
    __syncthreads();

    const int k0 = (tid & 15) * 8;
    const int r0 = (tid >> 4) * 4;

    float acc[4][8];
    #pragma unroll
    for (int r = 0; r < 4; ++r)
        #pragma unroll
        for (int k = 0; k < 8; ++k) acc[r][k] = 0.f;

#define ROWFMA(XR, R)                                                       \
    { float t;                                                              \
      t = fmaf(XR, ua.x, -ca.x); acc[R][0] = fmaf(t, t, acc[R][0]);         \
      t = fmaf(XR, ua.y, -ca.y); acc[R][1] = fmaf(t, t, acc[R][1]);         \
      t = fmaf(XR, ua.z, -ca.z); acc[R][2] = fmaf(t, t, acc[R][2]);         \
      t = fmaf(XR, ua.w, -ca.w); acc[R][3] = fmaf(t, t, acc[R][3]);         \
      t = fmaf(XR, ub.x, -cb.x); acc[R][4] = fmaf(t, t, acc[R][4]);         \
      t = fmaf(XR, ub.y, -cb.y); acc[R][5] = fmaf(t, t, acc[R][5]);         \
      t = fmaf(XR, ub.z, -cb.z); acc[R][6] = fmaf(t, t, acc[R][6]);         \
      t = fmaf(XR, ub.w, -cb.w); acc[R][7] = fmaf(t, t, acc[R][7]); }

    #pragma unroll
    for (int d = 0; d < DLEN; ++d) {
        const float4 ua = *reinterpret_cast<const float4*>(&sa[d][k0]);
        const float4 ub = *reinterpret_cast<const float4*>(&sa[d][k0 + 4]);
        const float4 ca = *reinterpret_cast<const float4*>(&sb[d][k0]);
        const float4 cb = *reinterpret_cast<const float4*>(&sb[d][k0 + 4]);
        const float4 xa = *reinterpret_cast<const float4*>(&xs[d][r0]);
        ROWFMA(xa.x, 0)
        ROWFMA(xa.y, 1)
        ROWFMA(xa.z, 2)
        ROWFMA(xa.w, 3)
    }
#undef ROWFMA

    // ---- write f16 partials (each element written by exactly one thread) ----
    #pragma unroll
    for (int r = 0; r < 4; ++r) {
        __half2* p = reinterpret_cast<__half2*>(
            &part[((size_t)ds * TB + b0 + r0 + r) * TK + k0]);
        p[0] = __floats2half2_rn(acc[r][0], acc[r][1]);
        p[1] = __floats2half2_rn(acc[r][2], acc[r][3]);
        p[2] = __floats2half2_rn(acc[r][4], acc[r][5]);
        p[3] = __floats2half2_rn(acc[r][6], acc[r][7]);
    }
}

// ---------------------------------------------------------------------------
// Finish: sum partials + det partials, log-softmax over k, argmax + dist.
// 4 waves/block, 1 row per wave, lane handles k = 2*lane, 2*lane+1.
// ---------------------------------------------------------------------------
__global__ __launch_bounds__(256) void finish_kernel(
        const __half* __restrict__ part, const float* __restrict__ logdet_part,
        float* __restrict__ out) {
    const int lane = threadIdx.x & 63;
    const int wv = threadIdx.x >> 6;
    const int b = blockIdx.x * 4 + wv;
    const int k0 = lane * 2;

    const __half2* ph = reinterpret_cast<const __half2*>(part);

    float d0 = 0.f, d1 = 0.f;
    float det0 = 0.f, det1 = 0.f;
    #pragma unroll 8
    for (int s = 0; s < DSPLIT; ++s) {
        float2 p = __half22float2(ph[(((size_t)s * TB + b) * TK >> 1) + lane]);
        d0 += p.x; d1 += p.y;
        float2 dt = *reinterpret_cast<const float2*>(&logdet_part[s * TK + k0]);
        det0 += dt.x; det1 += dt.y;
    }
    float s0 = fmaf(-0.5f, d0, det0);
    float s1 = fmaf(-0.5f, d1, det1);

    float m = fmaxf(s0, s1);
    #pragma unroll
    for (int msk = 32; msk >= 1; msk >>= 1) m = fmaxf(m, __shfl_xor(m, msk, 64));
    float p0 = expf(s0 - m), p1 = expf(s1 - m);
    float ps = p0 + p1;
    #pragma unroll
    for (int msk = 32; msk >= 1; msk >>= 1) ps += __shfl_xor(ps, msk, 64);
    float lse = logf(ps) + m;

    const float LOGC = -18.420680743952367f;  // ln(1e-8)
    float2 o;
    o.x = fmaxf(s0 - lse, LOGC);
    o.y = fmaxf(s1 - lse, LOGC);
    *reinterpret_cast<float2*>(&out[(size_t)b * TK + k0]) = o;

    // Argmax over s (first index on ties), carrying dist_sq.
    float bv; int bi; float bd;
    if (s1 > s0) { bv = s1; bi = k0 + 1; bd = d1; }
    else         { bv = s0; bi = k0;     bd = d0; }
    #pragma unroll
    for (int msk = 32; msk >= 1; msk >>= 1) {
        float ov = __shfl_xor(bv, msk, 64);
        int   oi = __shfl_xor(bi, msk, 64);
        float od = __shfl_xor(bd, msk, 64);
        if (ov > bv || (ov == bv && oi < bi)) { bv = ov; bi = oi; bd = od; }
    }
    if (lane == 0) out[(size_t)TB * TK + b] = sqrtf(bd);
}

// ---------------------------------------------------------------------------
extern "C" void kernel_launch(void* const* d_in, const int* in_sizes, int n_in,
                              void* d_out, int out_size, void* d_ws, size_t ws_size,
                              hipStream_t stream) {
    const float* x  = (const float*)d_in[0];
    const float* C  = (const float*)d_in[1];
    const float* Dm = (const float*)d_in[2];
    float* out = (float*)d_out;

    __half* part       = (__half*)d_ws;                          // 16 MB
    float* logdet_part = (float*)((char*)d_ws + (16ull << 20));  // 16 KB

    dist_kernel<<<NRB * DSPLIT, 256, 0, stream>>>(x, C, Dm, part, logdet_part);
    finish_kernel<<<TB / 4, 256, 0, stream>>>(part, logdet_part, out);
}

// Round 8
// 25.309 us; speedup vs baseline: 5.4841x; 5.4841x over previous
//
#include <hip/hip_runtime.h>
#include <hip/hip_fp16.h>
#include <math.h>

#define TB 2048
#define TK 128
#define TD 512
#define DSPLIT 32
#define DLEN 16            // TD / DSPLIT
#define BROWS 64
#define NRB (TB / BROWS)   // 32

// ws layout: [0, 16MB) part[ds][b][k] __half ; [16MB, +16KB) logdet_part[ds][k] f32

// ---------------------------------------------------------------------------
// dist kernel: block = 64 rows x 128 k x 16 d; 128 threads (2 waves).
// grid = 32 rb x 32 ds = 1024 blocks = 4 blocks/CU = 8 waves/CU (2/SIMD).
// Thread tile = 16 rows x 4 k  ->  param ds_read_b128 at 16-B lane stride
// (conflict-free), x reads broadcast. Partial stores: one 8-B uint2 per row
// per thread, 32 lanes contiguous (fixes R7's 268 MB write-allocate storm).
// blockIdx = rb*32+ds keeps same-ds blocks on one XCD (32 % 8 == 0) for
// param L2 reuse.
// ---------------------------------------------------------------------------
__global__ __launch_bounds__(128, 2) void dist_kernel(
        const float* __restrict__ x, const float* __restrict__ C,
        const float* __restrict__ Dm, __half* __restrict__ part,
        float* __restrict__ logdet_part) {
    __shared__ float sa[DLEN][TK];    // 8 KB : u = rsqrt(|D|+eps), [d][k]
    __shared__ float sb[DLEN][TK];    // 8 KB : c*u, [d][k]
    __shared__ float xs[DLEN][BROWS]; // 4 KB : x transposed, [d][row]

    const int tid = threadIdx.x;
    const int rb = blockIdx.x / DSPLIT;
    const int ds = blockIdx.x % DSPLIT;
    const int b0 = rb * BROWS;
    const int d0 = ds * DLEN;

    // ---- stage x transposed: 64 rows x 16 d = 256 f4, 2 per thread ----
    #pragma unroll
    for (int i = 0; i < 2; ++i) {
        int f = i * 128 + tid;         // 0..255
        int row = f >> 2;              // 0..63
        int dq = (f & 3) * 4;          // 0,4,8,12
        float4 v = *reinterpret_cast<const float4*>(
            &x[(size_t)(b0 + row) * TD + d0 + dq]);
        xs[dq + 0][row] = v.x;
        xs[dq + 1][row] = v.y;
        xs[dq + 2][row] = v.z;
        xs[dq + 3][row] = v.w;
    }

    // ---- stage params: 128 k x 4 f4 per array, 4 per thread (coalesced) ----
    #pragma unroll
    for (int i = 0; i < 4; ++i) {
        int f = i * 128 + tid;         // 0..511
        int k = f >> 2;                // 0..127
        int j = f & 3;                 // f4 index within k's 16-d slice
        float4 dv = *reinterpret_cast<const float4*>(&Dm[(size_t)k * TD + d0 + j * 4]);
        float4 cv = *reinterpret_cast<const float4*>(&C[(size_t)k * TD + d0 + j * 4]);
        float da0 = fabsf(dv.x) + 1e-8f, u0 = rsqrtf(da0);
        float da1 = fabsf(dv.y) + 1e-8f, u1 = rsqrtf(da1);
        float da2 = fabsf(dv.z) + 1e-8f, u2 = rsqrtf(da2);
        float da3 = fabsf(dv.w) + 1e-8f, u3 = rsqrtf(da3);
        int db = j * 4;
        sa[db + 0][k] = u0; sb[db + 0][k] = cv.x * u0;
        sa[db + 1][k] = u1; sb[db + 1][k] = cv.y * u1;
        sa[db + 2][k] = u2; sb[db + 2][k] = cv.z * u2;
        sa[db + 3][k] = u3; sb[db + 3][k] = cv.w * u3;
        if (rb == 0) {
            // 4 consecutive lanes (j=0..3) share k.
            float ls = logf(da0) + logf(da1) + logf(da2) + logf(da3);
            ls += __shfl_xor(ls, 1, 64);
            ls += __shfl_xor(ls, 2, 64);
            if ((tid & 3) == 0) logdet_part[ds * TK + k] = -0.5f * ls;
        }
    }
    __syncthreads();

    const int k0 = (tid & 31) * 4;     // 32 k-lanes x 4 k
    const int r0 = (tid >> 5) * 16;    // 4 row-groups x 16 rows

    float acc[16][4];
    #pragma unroll
    for (int r = 0; r < 16; ++r)
        #pragma unroll
        for (int k = 0; k < 4; ++k) acc[r][k] = 0.f;

#define ROWFMA(XR, R)                                                      \
    { float t;                                                             \
      t = fmaf(XR, u4.x, -c4.x); acc[R][0] = fmaf(t, t, acc[R][0]);        \
      t = fmaf(XR, u4.y, -c4.y); acc[R][1] = fmaf(t, t, acc[R][1]);        \
      t = fmaf(XR, u4.z, -c4.z); acc[R][2] = fmaf(t, t, acc[R][2]);        \
      t = fmaf(XR, u4.w, -c4.w); acc[R][3] = fmaf(t, t, acc[R][3]); }

    #pragma unroll
    for (int d = 0; d < DLEN; ++d) {
        const float4 u4 = *reinterpret_cast<const float4*>(&sa[d][k0]);
        const float4 c4 = *reinterpret_cast<const float4*>(&sb[d][k0]);
        const float4 xv0 = *reinterpret_cast<const float4*>(&xs[d][r0]);
        const float4 xv1 = *reinterpret_cast<const float4*>(&xs[d][r0 + 4]);
        const float4 xv2 = *reinterpret_cast<const float4*>(&xs[d][r0 + 8]);
        const float4 xv3 = *reinterpret_cast<const float4*>(&xs[d][r0 + 12]);
        ROWFMA(xv0.x, 0)  ROWFMA(xv0.y, 1)  ROWFMA(xv0.z, 2)  ROWFMA(xv0.w, 3)
        ROWFMA(xv1.x, 4)  ROWFMA(xv1.y, 5)  ROWFMA(xv1.z, 6)  ROWFMA(xv1.w, 7)
        ROWFMA(xv2.x, 8)  ROWFMA(xv2.y, 9)  ROWFMA(xv2.z, 10) ROWFMA(xv2.w, 11)
        ROWFMA(xv3.x, 12) ROWFMA(xv3.y, 13) ROWFMA(xv3.z, 14) ROWFMA(xv3.w, 15)
    }
#undef ROWFMA

    // ---- f16 partials: one contiguous 8-B store per row per thread ----
    #pragma unroll
    for (int r = 0; r < 16; ++r) {
        __half2 h0 = __floats2half2_rn(acc[r][0], acc[r][1]);
        __half2 h1 = __floats2half2_rn(acc[r][2], acc[r][3]);
        uint2 pk;
        pk.x = *reinterpret_cast<unsigned int*>(&h0);
        pk.y = *reinterpret_cast<unsigned int*>(&h1);
        *reinterpret_cast<uint2*>(
            &part[((size_t)ds * TB + b0 + r0 + r) * TK + k0]) = pk;
    }
}

// ---------------------------------------------------------------------------
// Finish: sum partials + det partials, log-softmax over k, argmax + dist.
// 4 waves/block, 1 row per wave, lane handles k = 2*lane, 2*lane+1.
// ---------------------------------------------------------------------------
__global__ __launch_bounds__(256) void finish_kernel(
        const __half* __restrict__ part, const float* __restrict__ logdet_part,
        float* __restrict__ out) {
    const int lane = threadIdx.x & 63;
    const int wv = threadIdx.x >> 6;
    const int b = blockIdx.x * 4 + wv;
    const int k0 = lane * 2;

    const __half2* ph = reinterpret_cast<const __half2*>(part);

    float d0 = 0.f, d1 = 0.f;
    float det0 = 0.f, det1 = 0.f;
    #pragma unroll 8
    for (int s = 0; s < DSPLIT; ++s) {
        float2 p = __half22float2(ph[(((size_t)s * TB + b) * TK >> 1) + lane]);
        d0 += p.x; d1 += p.y;
        float2 dt = *reinterpret_cast<const float2*>(&logdet_part[s * TK + k0]);
        det0 += dt.x; det1 += dt.y;
    }
    float s0 = fmaf(-0.5f, d0, det0);
    float s1 = fmaf(-0.5f, d1, det1);

    float m = fmaxf(s0, s1);
    #pragma unroll
    for (int msk = 32; msk >= 1; msk >>= 1) m = fmaxf(m, __shfl_xor(m, msk, 64));
    float p0 = expf(s0 - m), p1 = expf(s1 - m);
    float ps = p0 + p1;
    #pragma unroll
    for (int msk = 32; msk >= 1; msk >>= 1) ps += __shfl_xor(ps, msk, 64);
    float lse = logf(ps) + m;

    const float LOGC = -18.420680743952367f;  // ln(1e-8)
    float2 o;
    o.x = fmaxf(s0 - lse, LOGC);
    o.y = fmaxf(s1 - lse, LOGC);
    *reinterpret_cast<float2*>(&out[(size_t)b * TK + k0]) = o;

    // Argmax over s (first index on ties), carrying dist_sq.
    float bv; int bi; float bd;
    if (s1 > s0) { bv = s1; bi = k0 + 1; bd = d1; }
    else         { bv = s0; bi = k0;     bd = d0; }
    #pragma unroll
    for (int msk = 32; msk >= 1; msk >>= 1) {
        float ov = __shfl_xor(bv, msk, 64);
        int   oi = __shfl_xor(bi, msk, 64);
        float od = __shfl_xor(bd, msk, 64);
        if (ov > bv || (ov == bv && oi < bi)) { bv = ov; bi = oi; bd = od; }
    }
    if (lane == 0) out[(size_t)TB * TK + b] = sqrtf(bd);
}

// ---------------------------------------------------------------------------
extern "C" void kernel_launch(void* const* d_in, const int* in_sizes, int n_in,
                              void* d_out, int out_size, void* d_ws, size_t ws_size,
                              hipStream_t stream) {
    const float* x  = (const float*)d_in[0];
    const float* C  = (const float*)d_in[1];
    const float* Dm = (const float*)d_in[2];
    float* out = (float*)d_out;

    __half* part       = (__half*)d_ws;                          // 16 MB
    float* logdet_part = (float*)((char*)d_ws + (16ull << 20));  // 16 KB

    dist_kernel<<<NRB * DSPLIT, 128, 0, stream>>>(x, C, Dm, part, logdet_part);
    finish_kernel<<<TB / 4, 256, 0, stream>>>(part, logdet_part, out);
}